// Round 2
// baseline (636.852 us; speedup 1.0000x reference)
//
#include <hip/hip_runtime.h>
#include <cfloat>

// Problem constants (from reference): FACTOR=3, IPS=64, BP=5
//   CENTER=72, LO=57, HI=87(excl), NEW_CENTER=57, ALIGNED_LEN=192, L=220
#define LCOLS        220
#define WIN_LO       57
#define WIN_HI       86     // inclusive
#define ALIGNED_LEN_ 192
#define MAX_START    28     // L - ALIGNED_LEN
#define IPS_         64
#define NEW_CENTER_  57
#define TILE_ROWS    64
#define TILE_WORDS   (TILE_ROWS * LCOLS)   // 14080 floats = 56320 B (= 55 * 1024)

// Async global->LDS, 16 B per lane. LDS dest is wave-uniform base; lane i's
// data lands at base + i*16 (m104 semantics) — our LDS layout is byte-for-byte
// the global layout, so this is exact.
__device__ __forceinline__ void async_copy16(const float* gsrc, float* ldst) {
    __builtin_amdgcn_global_load_lds(
        (const __attribute__((address_space(1))) void*)gsrc,
        (__attribute__((address_space(3))) void*)ldst, 16, 0, 0);
}

__global__ __launch_bounds__(64) void peak_align_tile(
    const float* __restrict__ in,
    float* __restrict__ out_spikes,   // [K, 64]
    float* __restrict__ out_mask,     // [K]
    int K)
{
    __shared__ __align__(16) float tile[TILE_WORDS];
    __shared__ int srow[TILE_ROWS];   // packed: s | (valid << 30)

    const int lane = threadIdx.x;                 // block = 64 -> one wave
    const long long base = (long long)blockIdx.x * TILE_ROWS;
    const int rows = (int)(((long long)K - base) < TILE_ROWS ? (K - base) : TILE_ROWS);
    const float* src = in + base * LCOLS;

    // ---- Phase 1: stage rows*880 B contiguous global -> LDS ----
    const int bytes = rows * (LCOLS * 4);
    const int nfull = bytes >> 10;                // full 1024 B chunks (55 for full tile)
    for (int it = 0; it < nfull; ++it) {
        async_copy16(src + (it << 8) + lane * 4, &tile[it << 8]);
    }
    const int rem = bytes - (nfull << 10);        // only nonzero for the last tile
    if (lane * 16 < rem) {
        const float4 v = *(const float4*)(src + (nfull << 8) + lane * 4);
        *(float4*)&tile[(nfull << 8) + lane * 4] = v;
    }
    __syncthreads();  // compiler emits s_waitcnt vmcnt(0) lgkmcnt(0) before barrier

    // ---- Phase 2: each thread scans its own row (no shuffles) ----
    // b128 bank groups: (tid*55 + j) mod 8, 55 odd, j uniform -> conflict-free.
    int  s_val = 0;
    bool valid = false;
    if (lane < rows) {
        const float* row = &tile[lane * LCOLS];   // 880 B offset, 16 B aligned

        // pass 1: first-occurrence argmax over cols [57, 86]  (float4s 14..21)
        float bv = -FLT_MAX; int bi = WIN_LO;
        #pragma unroll
        for (int j = 14; j <= 21; ++j) {
            const float4 q = *(const float4*)(row + (j << 2));
            const float qq[4] = {q.x, q.y, q.z, q.w};
            #pragma unroll
            for (int k = 0; k < 4; ++k) {
                const int c = (j << 2) + k;
                if (c >= WIN_LO && c <= WIN_HI && qq[k] > bv) { bv = qq[k]; bi = c; }
            }
        }
        const int  start = bi - WIN_LO;           // in [0, 29]
        const bool in_b  = (start <= MAX_START);
        const int  s     = in_b ? start : MAX_START;

        // pass 2: first-occurrence argmax over cols [s, s+192)
        float av = -FLT_MAX; int ai = -1;
        #pragma unroll 5
        for (int j = 0; j < 55; ++j) {
            const float4 q = *(const float4*)(row + (j << 2));
            const float qq[4] = {q.x, q.y, q.z, q.w};
            #pragma unroll
            for (int k = 0; k < 4; ++k) {
                const int c = (j << 2) + k;
                const bool inr = (unsigned)(c - s) < (unsigned)ALIGNED_LEN_;
                if (inr && qq[k] > av) { av = qq[k]; ai = c; }
            }
        }
        valid = in_b && (ai == s + NEW_CENTER_);
        s_val = s;
    }
    srow[lane] = s_val | (valid ? (1 << 30) : 0);
    __syncthreads();

    // ---- Phase 3: per-row coalesced gather + 256 B contiguous stores ----
    // gather banks: (3*lane + const) mod 32 -> 2 lanes/bank (free, m136)
    for (int rr = 0; rr < rows; ++rr) {
        const int pk = srow[rr];                  // LDS broadcast read
        const int s  = pk & 0xFFFF;
        const float v = tile[rr * LCOLS + s + 3 * lane];
        out_spikes[(base + rr) * IPS_ + lane] = (pk & (1 << 30)) ? v : 0.0f;
    }
    if (lane < rows) out_mask[base + lane] = valid ? 0.0f : 1.0f;  // removed_mask = ~valid
}

extern "C" void kernel_launch(void* const* d_in, const int* in_sizes, int n_in,
                              void* d_out, int out_size, void* d_ws, size_t ws_size,
                              hipStream_t stream) {
    const float* in = (const float*)d_in[0];
    const int K = in_sizes[0] / LCOLS;            // 500000

    float* out_spikes = (float*)d_out;
    float* out_mask   = out_spikes + (long long)K * IPS_;

    const int grid = (K + TILE_ROWS - 1) / TILE_ROWS;   // 7813 tiles
    hipLaunchKernelGGL(peak_align_tile, dim3(grid), dim3(TILE_ROWS), 0, stream,
                       in, out_spikes, out_mask, K);
}

// Round 3
// 601.211 us; speedup vs baseline: 1.0593x; 1.0593x over previous
//
#include <hip/hip_runtime.h>
#include <cfloat>

// Problem constants (from reference): FACTOR=3, IPS=64, BP=5
//   CENTER=72, LO=57, HI=87(excl), NEW_CENTER=57, ALIGNED_LEN=192, L=220
#define LCOLS        220
#define NF4          55     // float4s per row
#define WIN_LO       57
#define WIN_HI       86     // inclusive
#define ALIGNED_LEN_ 192
#define MAX_START    28     // L - ALIGNED_LEN
#define IPS_         64
#define NEW_CENTER_  57
#define TILE_ROWS    64
#define TILE_WORDS   (TILE_ROWS * LCOLS)   // 14080 floats = 56320 B

// Quarter boundaries in float4 units: [0,14) [14,28) [28,42) [42,55)
__device__ __constant__ int Q_LO[4] = {0, 14, 28, 42};
__device__ __constant__ int Q_HI[4] = {14, 28, 42, 55};

__device__ __forceinline__ void async_copy16(const float* gsrc, float* ldst) {
    __builtin_amdgcn_global_load_lds(
        (const __attribute__((address_space(1))) void*)gsrc,
        (__attribute__((address_space(3))) void*)ldst, 16, 0, 0);
}

__global__ __launch_bounds__(256, 2) void peak_align_tile(
    const float* __restrict__ in,
    float* __restrict__ out_spikes,   // [K, 64]
    float* __restrict__ out_mask,     // [K]
    int K)
{
    __shared__ __align__(16) float tile[TILE_WORDS];
    __shared__ int   spack[TILE_ROWS];     // s | (in_b << 8)   (phase 2a -> 2b)
    __shared__ float pval[256];            // per-quarter partial argmax val
    __shared__ int   pidx[256];            // per-quarter partial argmax idx
    __shared__ int   rpack[TILE_ROWS];     // s | (valid << 30) (phase 2c -> 3)

    const int t    = threadIdx.x;
    const int lane = t & 63;
    const int wave = t >> 6;               // = quarter q for phase 2b
    const long long base = (long long)blockIdx.x * TILE_ROWS;
    const int rows = (int)(((long long)K - base) < TILE_ROWS ? (K - base) : TILE_ROWS);
    const float* src = in + base * LCOLS;

    // ---- Phase 1: stage rows*880 B contiguous global -> LDS (4 waves) ----
    const int bytes = rows * (LCOLS * 4);
    const int nfull = bytes >> 10;                  // 1 KB chunks (55 full tile)
    for (int it = wave; it < nfull; it += 4) {
        async_copy16(src + (it << 8) + lane * 4, &tile[it << 8]);
    }
    const int rem = bytes - (nfull << 10);
    if (t * 16 < rem) {
        const float4 v = *(const float4*)(src + (nfull << 8) + t * 4);
        *(float4*)&tile[(nfull << 8) + t * 4] = v;
    }
    __syncthreads();

    // ---- Phase 2a: window argmax, cols [57,86] (all inside quarter 1).
    // Wave 1 only: thread (wave==1, lane=r) scans row r, f4 14..21.
    if (wave == 1 && lane < rows) {
        const float* row = &tile[lane * LCOLS];
        float bv = -FLT_MAX; int bi = WIN_LO;
        #pragma unroll
        for (int j = 14; j <= 21; ++j) {
            const float4 q = *(const float4*)(row + (j << 2));
            const float qq[4] = {q.x, q.y, q.z, q.w};
            #pragma unroll
            for (int k = 0; k < 4; ++k) {
                const int c = (j << 2) + k;
                if (c >= WIN_LO && c <= WIN_HI && qq[k] > bv) { bv = qq[k]; bi = c; }
            }
        }
        const int  start = bi - WIN_LO;             // [0, 29]
        const bool in_b  = (start <= MAX_START);
        spack[lane] = (in_b ? start : MAX_START) | (in_b ? (1 << 8) : 0);
    }
    __syncthreads();

    // ---- Phase 2b: aligned-window argmax over [s, s+192), quarter-split.
    // Thread (wave=q, lane=r): scan f4 [Q_LO[q], Q_HI[q]) of row r.
    {
        float av = -FLT_MAX; int ai = 0x7fffffff;
        if (lane < rows) {
            const int  pk = spack[lane];
            const int  s  = pk & 0xFF;
            const float* row = &tile[lane * LCOLS];
            const int jlo = Q_LO[wave], jhi = Q_HI[wave];
            for (int j = jlo; j < jhi; ++j) {
                const float4 q = *(const float4*)(row + (j << 2));
                const float qq[4] = {q.x, q.y, q.z, q.w};
                #pragma unroll
                for (int k = 0; k < 4; ++k) {
                    const int c = (j << 2) + k;
                    const bool inr = (unsigned)(c - s) < (unsigned)ALIGNED_LEN_;
                    if (inr && qq[k] > av) { av = qq[k]; ai = c; }
                }
            }
        }
        pval[t] = av; pidx[t] = ai;
    }
    __syncthreads();

    // ---- Phase 2c: combine 4 quarters (first occurrence), wave 0 only ----
    if (wave == 0 && lane < rows) {
        float av = pval[lane];      int ai = pidx[lane];
        #pragma unroll
        for (int q = 1; q < 4; ++q) {
            const float v2 = pval[q * 64 + lane];
            const int   i2 = pidx[q * 64 + lane];
            if (v2 > av || (v2 == av && i2 < ai)) { av = v2; ai = i2; }
        }
        const int  pk    = spack[lane];
        const int  s     = pk & 0xFF;
        const bool in_b  = (pk >> 8) != 0;
        const bool valid = in_b && (ai == s + NEW_CENTER_);
        rpack[lane] = s | (valid ? (1 << 30) : 0);
        out_mask[base + lane] = valid ? 0.0f : 1.0f;   // removed_mask = ~valid
    }
    __syncthreads();

    // ---- Phase 3: gather + store, 16 rows per wave ----
    // banks: (3*lane + const) mod 32 -> 2 lanes/bank (free, m136)
    for (int i = 0; i < 16; ++i) {
        const int rr = wave * 16 + i;
        if (rr < rows) {
            const int pk = rpack[rr];
            const int s  = pk & 0xFF;
            const float v = tile[rr * LCOLS + s + 3 * lane];
            out_spikes[(base + rr) * IPS_ + lane] = (pk & (1 << 30)) ? v : 0.0f;
        }
    }
}

extern "C" void kernel_launch(void* const* d_in, const int* in_sizes, int n_in,
                              void* d_out, int out_size, void* d_ws, size_t ws_size,
                              hipStream_t stream) {
    const float* in = (const float*)d_in[0];
    const int K = in_sizes[0] / LCOLS;            // 500000

    float* out_spikes = (float*)d_out;
    float* out_mask   = out_spikes + (long long)K * IPS_;

    const int grid = (K + TILE_ROWS - 1) / TILE_ROWS;   // 7813
    hipLaunchKernelGGL(peak_align_tile, dim3(grid), dim3(256), 0, stream,
                       in, out_spikes, out_mask, K);
}

// Round 4
// 594.736 us; speedup vs baseline: 1.0708x; 1.0109x over previous
//
#include <hip/hip_runtime.h>
#include <cfloat>

// Problem constants (from reference): FACTOR=3, IPS=64, BP=5
//   CENTER=72, LO=57, HI=87(excl), NEW_CENTER=57, ALIGNED_LEN=192, L=220
#define LCOLS        220
#define WIN_LO       57
#define WIN_HI       86     // inclusive
#define ALIGNED_LEN_ 192
#define MAX_START    28     // L - ALIGNED_LEN
#define IPS_         64
#define NEW_CENTER_  57
#define TILE_ROWS    32
#define TILE_WORDS   (TILE_ROWS * LCOLS)   // 7040 floats = 28160 B

__device__ __forceinline__ void async_copy16(const float* gsrc, float* ldst) {
    __builtin_amdgcn_global_load_lds(
        (const __attribute__((address_space(1))) void*)gsrc,
        (__attribute__((address_space(3))) void*)ldst, 16, 0, 0);
}

// Block = 128 (2 waves), tile = 32 rows. LDS ~29.4 KB -> 5 blocks/CU.
__global__ __launch_bounds__(128) void peak_align_tile(
    const float* __restrict__ in,
    float* __restrict__ out_spikes,   // [K, 64]
    float* __restrict__ out_mask,     // [K]
    int K)
{
    __shared__ __align__(16) float tile[TILE_WORDS];
    __shared__ int   spack[TILE_ROWS];   // s | (in_b << 8)
    __shared__ float pval[128];          // per-quarter partial argmax val
    __shared__ int   pidx[128];          // per-quarter partial argmax idx
    __shared__ int   rpack[TILE_ROWS];   // s | (valid << 30)

    const int t    = threadIdx.x;
    const int lane = t & 63;
    const int wave = t >> 6;                         // 0 or 1
    const long long base = (long long)blockIdx.x * TILE_ROWS;
    const int rows = (int)(((long long)K - base) < TILE_ROWS ? (K - base) : TILE_ROWS);
    const float* src = in + base * LCOLS;

    // ---- Phase 1: stage rows*880 B contiguous global -> LDS (2 waves) ----
    const int bytes = rows * (LCOLS * 4);            // 28160 for full tile
    const int nfull = bytes >> 10;                   // 27 full 1 KB chunks
    for (int it = wave; it < nfull; it += 2) {
        async_copy16(src + (it << 8) + lane * 4, &tile[it << 8]);
    }
    const int rem = bytes - (nfull << 10);           // 512 B tail (full tile)
    if (t * 16 < rem) {
        const float4 v = *(const float4*)(src + (nfull << 8) + t * 4);
        *(float4*)&tile[(nfull << 8) + t * 4] = v;
    }
    __syncthreads();

    // ---- Phase 2a: window argmax, cols [57,86] (f4 14..21), 32 threads ----
    if (t < rows) {
        const float* row = &tile[t * LCOLS];
        float bv = -FLT_MAX; int bi = WIN_LO;
        #pragma unroll
        for (int j = 14; j <= 21; ++j) {
            const float4 q = *(const float4*)(row + (j << 2));
            const float qq[4] = {q.x, q.y, q.z, q.w};
            #pragma unroll
            for (int k = 0; k < 4; ++k) {
                const int c = (j << 2) + k;
                if (c >= WIN_LO && c <= WIN_HI && qq[k] > bv) { bv = qq[k]; bi = c; }
            }
        }
        const int  start = bi - WIN_LO;              // [0, 29]
        const bool in_b  = (start <= MAX_START);
        spack[t] = (in_b ? start : MAX_START) | (in_b ? (1 << 8) : 0);
    }
    __syncthreads();

    // ---- Phase 2b: aligned argmax over [s, s+192), quarter-split ----
    // thread t: row r = t&31, quarter q = t>>5 (f4 [14q, 14q+14), q3: [42,55))
    {
        const int r = t & 31;
        const int q = t >> 5;
        const int jlo = q * 14;
        const int jhi = (q == 3) ? 55 : jlo + 14;
        float av = -FLT_MAX; int ai = 0x7fffffff;
        if (r < rows) {
            const int s = spack[r] & 0xFF;
            const float* row = &tile[r * LCOLS];
            for (int j = jlo; j < jhi; ++j) {
                const float4 qv = *(const float4*)(row + (j << 2));
                const float qq[4] = {qv.x, qv.y, qv.z, qv.w};
                #pragma unroll
                for (int k = 0; k < 4; ++k) {
                    const int c = (j << 2) + k;
                    const bool inr = (unsigned)(c - s) < (unsigned)ALIGNED_LEN_;
                    if (inr && qq[k] > av) { av = qq[k]; ai = c; }
                }
            }
        }
        pval[t] = av; pidx[t] = ai;
    }
    __syncthreads();

    // ---- Phase 2c: combine quarters (first occurrence), 32 threads ----
    if (t < rows) {
        float av = pval[t];        int ai = pidx[t];
        #pragma unroll
        for (int q = 1; q < 4; ++q) {
            const float v2 = pval[q * 32 + t];
            const int   i2 = pidx[q * 32 + t];
            if (v2 > av || (v2 == av && i2 < ai)) { av = v2; ai = i2; }
        }
        const int  pk    = spack[t];
        const int  s     = pk & 0xFF;
        const bool in_b  = (pk >> 8) != 0;
        const bool valid = in_b && (ai == s + NEW_CENTER_);
        rpack[t] = s | (valid ? (1 << 30) : 0);
        out_mask[base + t] = valid ? 0.0f : 1.0f;    // removed_mask = ~valid
    }
    __syncthreads();

    // ---- Phase 3: gather + store, 16 rows per wave ----
    // banks: (3*lane + const) mod 32 -> 2 lanes/bank (free, m136)
    #pragma unroll
    for (int i = 0; i < 16; ++i) {
        const int rr = wave * 16 + i;
        if (rr < rows) {
            const int pk = rpack[rr];
            const int s  = pk & 0xFF;
            const float v = tile[rr * LCOLS + s + 3 * lane];
            out_spikes[(base + rr) * IPS_ + lane] = (pk & (1 << 30)) ? v : 0.0f;
        }
    }
}

extern "C" void kernel_launch(void* const* d_in, const int* in_sizes, int n_in,
                              void* d_out, int out_size, void* d_ws, size_t ws_size,
                              hipStream_t stream) {
    const float* in = (const float*)d_in[0];
    const int K = in_sizes[0] / LCOLS;               // 500000 = 32 * 15625

    float* out_spikes = (float*)d_out;
    float* out_mask   = out_spikes + (long long)K * IPS_;

    const int grid = (K + TILE_ROWS - 1) / TILE_ROWS;   // 15625
    hipLaunchKernelGGL(peak_align_tile, dim3(grid), dim3(128), 0, stream,
                       in, out_spikes, out_mask, K);
}